// Round 4
// baseline (945.123 us; speedup 1.0000x reference)
//
#include <hip/hip_runtime.h>
#include <stdint.h>
#include <stddef.h>

#define NL   4
#define CBC  256
#define DCH  512
#define KW   3
#define BATCH 16
#define TT   4096
#define BT   (BATCH*TT)
#define EPSB 1e-5f
#define DWT  32   // dwconv t-chunk per block

typedef __bf16 bf16_t;
typedef __attribute__((ext_vector_type(8))) __bf16 bf16x8;
typedef __attribute__((ext_vector_type(4))) float f32x4;
typedef __attribute__((ext_vector_type(8))) unsigned short us8;
typedef __attribute__((ext_vector_type(4))) unsigned short us4;

static __device__ __forceinline__ unsigned short f2bf(float f) {
    union { float f; uint32_t u; } v; v.f = f;
    uint32_t u = v.u;
    u += 0x7FFFu + ((u >> 16) & 1u);   // RNE
    return (unsigned short)(u >> 16);
}
static __device__ __forceinline__ float bf2f(unsigned short b) {
    union { uint32_t u; float f; } v; v.u = ((uint32_t)b) << 16;
    return v.f;
}
static __device__ __forceinline__ bf16x8 as_bf16x8(us8 u) {
    return __builtin_bit_cast(bf16x8, u);
}
static __device__ __forceinline__ float signf_(float w) {
    return (w > 0.f) ? 1.f : ((w < 0.f) ? -1.f : 0.f);
}

typedef __attribute__((address_space(1))) void as1_void;
typedef __attribute__((address_space(3))) void as3_void;
static __device__ __forceinline__ void gload_lds16(const unsigned short* g, unsigned short* l) {
    // 16B per lane, wave-uniform LDS base + lane*16 (guide §5: width=16 verified m97)
    __builtin_amdgcn_global_load_lds((as1_void*)g, (as3_void*)l, 16, 0, 0);
}

// ---------------------------------------------------------------------------
// Weight prep: sign(w1) -> bf16 [L][D][CB]; sign(wd) -> f32 [L][D][3]
// ---------------------------------------------------------------------------
__global__ void prep_kernel(const float* __restrict__ w1, const float* __restrict__ wd,
                            unsigned short* __restrict__ W1S, float* __restrict__ WDS) {
    const int NW1 = NL * DCH * CBC;
    const int NWD = NL * DCH * KW;
    int idx = blockIdx.x * 256 + threadIdx.x;
    if (idx < NW1) {
        W1S[idx] = f2bf(signf_(w1[idx]));
    } else if (idx < NW1 + NWD) {
        int j = idx - NW1;
        WDS[j] = signf_(wd[j]);
    }
}

// ---------------------------------------------------------------------------
// Input transpose: x [B][CB][T] f32  ->  XA [B*T][CB] bf16
// ---------------------------------------------------------------------------
__global__ void transpose_in(const float* __restrict__ x, unsigned short* __restrict__ XA) {
    __shared__ unsigned short tile[64][72];
    const int t0 = blockIdx.x * 64, c0 = blockIdx.y * 64, b = blockIdx.z;
    const int tid = threadIdx.x;
    {
        const int cl = tid >> 2;
        const int tl = (tid & 3) * 16;
        const float* src = x + ((size_t)(b * CBC + c0 + cl)) * TT + t0 + tl;
        #pragma unroll
        for (int u = 0; u < 16; u += 4) {
            float4 f = *(const float4*)(src + u);
            tile[cl][tl + u + 0] = f2bf(f.x);
            tile[cl][tl + u + 1] = f2bf(f.y);
            tile[cl][tl + u + 2] = f2bf(f.z);
            tile[cl][tl + u + 3] = f2bf(f.w);
        }
    }
    __syncthreads();
    {
        const int tr = tid >> 2;
        const int cc = (tid & 3) * 16;
        us8 o0, o1;
        #pragma unroll
        for (int e = 0; e < 8; ++e) { o0[e] = tile[cc + e][tr]; o1[e] = tile[cc + 8 + e][tr]; }
        unsigned short* dst = XA + ((size_t)(b * TT + t0 + tr)) * CBC + c0 + cc;
        *(us8*)dst = o0;
        *(us8*)(dst + 8) = o1;
    }
}

// ---------------------------------------------------------------------------
// GEMM: out[n][m] = sum_k A[m][k] * B[n][k] (+bias, optional PReLU)
// 128x128 tile, BK=32. Catalog-verified 2-phase double-buffer (T3 minimum
// recipe, m248v2): per iter {STAGE(next tile) -> ds_read(cur) -> MFMA ->
// vmcnt(0) -> s_barrier}. sched_barrier(0) after every waitcnt/barrier pins
// the schedule (rule #18). LDS XOR swizzle both-sides (rule #21).
// Grid: 1D, bijective XCD-chunked swizzle, m-tiles innermost (L2 B-reuse).
// UNCHANGED from round 3 (correctness- and perf-verified).
// ---------------------------------------------------------------------------
template<int K, int NMT, bool PRELU, bool FINAL, bool STATS>
__global__ __launch_bounds__(256, 4)
void gemm_kernel(const unsigned short* __restrict__ A,
                 const unsigned short* __restrict__ Bact,
                 const float* __restrict__ bias,
                 const float* __restrict__ aptr,
                 unsigned short* __restrict__ Obf,
                 float* __restrict__ Ofin,
                 const float* __restrict__ resid,
                 float* __restrict__ sums, float* __restrict__ sqs,
                 int M) {
    __shared__ union {
        unsigned short stage[2][4][2048];    // [buf][A0,A1,B0,B1][64 rows x 32] = 32KB
        unsigned short sout[128 * 136];      // epilogue transpose (34KB)
    } sm;
    __shared__ float sstat[2][4][64];        // [sum/sq][wave][ch_local]

    const int tid = threadIdx.x;

    // bijective XCD-chunked swizzle (nwg % 8 == 0 always here, m204)
    const int nwg = NMT * (TT / 128) * BATCH;
    const int orig = blockIdx.x;
    const int logical = (orig & 7) * (nwg >> 3) + (orig >> 3);
    const int mt = logical % NMT;            // m-tile innermost -> same-XCD B reuse
    const int rest = logical / NMT;
    const int tt = rest & 31;                // TT/128 = 32 t-tiles
    const int bz = rest >> 5;
    const int t0 = tt * 128;
    const int m0 = mt * 128;
    const size_t n0 = (size_t)bz * TT + t0;

    const int lane = tid & 63;
    const int w    = tid >> 6;
    const int wm = w & 1, wn = w >> 1;
    const int l16 = lane & 15, q = lane >> 4;

    // staging: thread tid covers half-tile row tid>>2, swizzled 16B chunk
    const int rS = tid >> 2;
    const int cS = ((tid & 3) ^ ((tid >> 3) & 3)) * 8;   // chunk ^ ((row>>1)&3)
    const unsigned short* gA0 = A + (size_t)(m0 + rS) * K + cS;
    const unsigned short* gA1 = A + (size_t)(m0 + 64 + rS) * K + cS;
    const unsigned short* gB0 = Bact + (n0 + rS) * K + cS;
    const unsigned short* gB1 = Bact + (n0 + 64 + rS) * K + cS;
    const int wofs = w << 9;                  // per-wave 512-short (1KB) slice

    auto STAGE = [&](int step, int buf) {
        const int k0 = step * 32;
        unsigned short* sb = &sm.stage[buf][0][0];
        gload_lds16(gA0 + k0, sb + 0 * 2048 + wofs);
        gload_lds16(gA1 + k0, sb + 1 * 2048 + wofs);
        gload_lds16(gB0 + k0, sb + 2 * 2048 + wofs);
        gload_lds16(gB1 + k0, sb + 3 * 2048 + wofs);
    };

    f32x4 acc[4][4];
    #pragma unroll
    for (int i = 0; i < 4; ++i)
        #pragma unroll
        for (int j = 0; j < 4; ++j)
            acc[i][j] = (f32x4){0.f, 0.f, 0.f, 0.f};

    // read-side swizzle: same XOR as write side; ((i*16+l16)>>1)&3 == (l16>>1)&3
    const int csw = (q ^ ((l16 >> 1) & 3)) << 3;

    constexpr int NK = K / 32;
    // prologue: stage tile 0, publish
    STAGE(0, 0);
    asm volatile("s_waitcnt vmcnt(0)" ::: "memory");
    __builtin_amdgcn_s_barrier();
    __builtin_amdgcn_sched_barrier(0);

    #pragma unroll
    for (int k = 0; k < NK; ++k) {
        const int cur = k & 1;
        // issue next-tile loads FIRST (latency hides under compute below).
        if (k + 1 < NK) STAGE(k + 1, cur ^ 1);
        const unsigned short* sb = &sm.stage[cur][0][0];
        bf16x8 af[4], bfv[4];
        #pragma unroll
        for (int i = 0; i < 4; ++i)
            af[i] = as_bf16x8(*(const us8*)(sb + wm * 2048 + (i * 16 + l16) * 32 + csw));
        #pragma unroll
        for (int j = 0; j < 4; ++j)
            bfv[j] = as_bf16x8(*(const us8*)(sb + (2 + wn) * 2048 + (j * 16 + l16) * 32 + csw));
        #pragma unroll
        for (int i = 0; i < 4; ++i)
            #pragma unroll
            for (int j = 0; j < 4; ++j)
                acc[i][j] = __builtin_amdgcn_mfma_f32_16x16x32_bf16(af[i], bfv[j], acc[i][j], 0, 0, 0);
        // publish next tile: own loads landed, then barrier => all waves' landed
        if (k + 1 < NK) {
            asm volatile("s_waitcnt vmcnt(0)" ::: "memory");
            __builtin_amdgcn_sched_barrier(0);
        }
        __builtin_amdgcn_s_barrier();
        __builtin_amdgcn_sched_barrier(0);
    }

    float alpha = 0.f;
    if constexpr (PRELU) alpha = aptr[0];

    if constexpr (FINAL) {
        #pragma unroll
        for (int i = 0; i < 4; ++i) {
            const int m_l = wm * 64 + i * 16 + q * 4;
            float bia[4];
            #pragma unroll
            for (int rg = 0; rg < 4; ++rg) bia[rg] = bias[m0 + m_l + rg];
            #pragma unroll
            for (int j = 0; j < 4; ++j) {
                const int n_l = wn * 64 + j * 16 + l16;
                const int t = t0 + n_l;
                #pragma unroll
                for (int rg = 0; rg < 4; ++rg) {
                    float v = acc[i][j][rg] + bia[rg];
                    size_t oidx = ((size_t)(bz * CBC + m0 + m_l + rg)) * TT + t;
                    Ofin[oidx] = v + resid[oidx];
                }
            }
        }
    } else {
        #pragma unroll
        for (int i = 0; i < 4; ++i) {
            const int m_l = wm * 64 + i * 16 + q * 4;
            float bia[4];
            #pragma unroll
            for (int rg = 0; rg < 4; ++rg) bia[rg] = bias[m0 + m_l + rg];
            #pragma unroll
            for (int j = 0; j < 4; ++j) {
                const int n_l = wn * 64 + j * 16 + l16;
                us4 pkv;
                #pragma unroll
                for (int rg = 0; rg < 4; ++rg) {
                    float v = acc[i][j][rg] + bia[rg];
                    if (PRELU) v = (v >= 0.f) ? v : alpha * v;
                    pkv[rg] = f2bf(v);
                }
                *(us4*)&sm.sout[n_l * 136 + m_l] = pkv;
            }
            if constexpr (STATS) {
                #pragma unroll
                for (int rg = 0; rg < 4; ++rg) {
                    float sv = 0.f, sq2 = 0.f;
                    #pragma unroll
                    for (int j = 0; j < 4; ++j) {
                        float v = acc[i][j][rg] + bia[rg];
                        if (PRELU) v = (v >= 0.f) ? v : alpha * v;
                        sv += v; sq2 += v * v;
                    }
                    #pragma unroll
                    for (int msk = 1; msk < 16; msk <<= 1) {
                        sv  += __shfl_xor(sv,  msk, 64);
                        sq2 += __shfl_xor(sq2, msk, 64);
                    }
                    if (l16 == 0) {
                        const int cl = i * 16 + q * 4 + rg;   // channel local to wm
                        sstat[0][w][cl] = sv;
                        sstat[1][w][cl] = sq2;
                    }
                }
            }
        }
        __syncthreads();
        const int rr = tid >> 4;
        const int c8 = (tid & 15) * 8;
        #pragma unroll
        for (int p = 0; p < 8; ++p) {
            const int n_l = p * 16 + rr;
            us8 v = *(const us8*)&sm.sout[n_l * 136 + c8];
            *(us8*)(Obf + (n0 + n_l) * M + m0 + c8) = v;
        }
        if constexpr (STATS) {
            if (tid < 128) {
                const int wmc = tid >> 6, cl = tid & 63;
                float S = sstat[0][wmc][cl] + sstat[0][wmc + 2][cl];
                float Q = sstat[1][wmc][cl] + sstat[1][wmc + 2][cl];
                atomicAdd(&sums[m0 + tid], S);
                atomicAdd(&sqs[m0 + tid], Q);
            }
        }
    }
}

// ---------------------------------------------------------------------------
// Depthwise dilated causal conv + bias + PReLU, fused Z-stats.
// BN1 finalize is FUSED: each lane computes scale/shift for its own 8
// channels from the raw sums/sqs (removes the bn_finalize launch).
// wd signs are exactly +-1/0, so folding BN1 scale into the tap weights
// (Wks = wk*s) is exact; shall = (w0+w1+w2)*sh + bd.
// Block 0 (t<32 >= 2*dil_max=16) keeps the conditional boundary path; all
// other blocks run an unconditional 2-deep software-pipelined body
// (next iter's 3 loads in flight under current compute -> latency hidden).
// grid = (TT/DWT, BATCH), block 256; wave w handles t = t0 + it*4 + w.
// ---------------------------------------------------------------------------
__global__ __launch_bounds__(256, 4)
void dwconv_kernel(const unsigned short* __restrict__ Y,
                   const float* __restrict__ sums1, const float* __restrict__ sqs1,
                   const float* __restrict__ g1, const float* __restrict__ be1,
                   const float* __restrict__ wds, const float* __restrict__ bd,
                   const float* __restrict__ a2p, int dil,
                   unsigned short* __restrict__ Z,
                   float* __restrict__ sums2, float* __restrict__ sqs2) {
    __shared__ float ssum[4][512];
    __shared__ float ssq[4][512];
    const int b = blockIdx.y;
    const int t0 = blockIdx.x * DWT;
    const int tid = threadIdx.x;
    const int w = tid >> 6;
    const int lane = tid & 63;
    const int c0 = lane * 8;
    const float alpha = a2p[0];
    constexpr int NIT = DWT / 4;

    // fused BN1 finalize (per-lane, 8 channels) + weights
    float s8[8], sh8[8], wv0[8], wv1[8], wv2[8], bb8[8];
    const float inv = 1.f / (float)BT;
    #pragma unroll
    for (int e = 0; e < 8; ++e) {
        const int d = c0 + e;
        float mean = sums1[d] * inv;
        float var = sqs1[d] * inv - mean * mean;
        float sc = g1[d] * rsqrtf(var + EPSB);
        s8[e] = sc;
        sh8[e] = be1[d] - mean * sc;
        wv0[e] = wds[d * 3 + 0]; wv1[e] = wds[d * 3 + 1]; wv2[e] = wds[d * 3 + 2];
        bb8[e] = bd[d];
    }

    float asum[8], asq[8];
    #pragma unroll
    for (int e = 0; e < 8; ++e) { asum[e] = 0.f; asq[e] = 0.f; }

    if (blockIdx.x == 0) {
        // boundary block: conditional taps (t < 2*dil possible)
        for (int it = 0; it < NIT; ++it) {
            const int t = t0 + it * 4 + w;
            const size_t base = ((size_t)b * TT + t) * DCH + c0;
            float acc[8];
            {
                us8 y0 = *(const us8*)&Y[base];
                #pragma unroll
                for (int e = 0; e < 8; ++e)
                    acc[e] = wv2[e] * (s8[e] * bf2f(y0[e]) + sh8[e]) + bb8[e];
            }
            if (t >= dil) {
                us8 y1 = *(const us8*)&Y[base - (size_t)dil * DCH];
                #pragma unroll
                for (int e = 0; e < 8; ++e)
                    acc[e] += wv1[e] * (s8[e] * bf2f(y1[e]) + sh8[e]);
            }
            if (t >= 2 * dil) {
                us8 y2 = *(const us8*)&Y[base - (size_t)(2 * dil) * DCH];
                #pragma unroll
                for (int e = 0; e < 8; ++e)
                    acc[e] += wv0[e] * (s8[e] * bf2f(y2[e]) + sh8[e]);
            }
            us8 o;
            #pragma unroll
            for (int e = 0; e < 8; ++e) {
                float v = acc[e];
                v = (v >= 0.f) ? v : alpha * v;
                asum[e] += v; asq[e] += v * v;
                o[e] = f2bf(v);
            }
            *(us8*)&Z[base] = o;
        }
    } else {
        // steady blocks: exact BN fold (w = +-1/0), unconditional, pipelined
        float W0s[8], W1s[8], W2s[8], shall[8];
        #pragma unroll
        for (int e = 0; e < 8; ++e) {
            W0s[e] = wv0[e] * s8[e];
            W1s[e] = wv1[e] * s8[e];
            W2s[e] = wv2[e] * s8[e];
            shall[e] = (wv0[e] + wv1[e] + wv2[e]) * sh8[e] + bb8[e];
        }
        const size_t base0 = ((size_t)b * TT + t0 + w) * DCH + c0;
        const size_t dstep = (size_t)4 * DCH;
        const size_t d1 = (size_t)dil * DCH, d2 = 2 * d1;

        us8 y0c = *(const us8*)&Y[base0];
        us8 y1c = *(const us8*)&Y[base0 - d1];
        us8 y2c = *(const us8*)&Y[base0 - d2];
        #pragma unroll
        for (int it = 0; it < NIT; ++it) {
            us8 y0n, y1n, y2n;
            if (it + 1 < NIT) {
                const size_t bn = base0 + (size_t)(it + 1) * dstep;
                y0n = *(const us8*)&Y[bn];
                y1n = *(const us8*)&Y[bn - d1];
                y2n = *(const us8*)&Y[bn - d2];
            }
            us8 o;
            #pragma unroll
            for (int e = 0; e < 8; ++e) {
                float v = W2s[e] * bf2f(y0c[e]) + W1s[e] * bf2f(y1c[e])
                        + W0s[e] * bf2f(y2c[e]) + shall[e];
                v = (v >= 0.f) ? v : alpha * v;
                asum[e] += v; asq[e] += v * v;
                o[e] = f2bf(v);
            }
            *(us8*)&Z[base0 + (size_t)it * dstep] = o;
            y0c = y0n; y1c = y1n; y2c = y2n;
        }
    }

    #pragma unroll
    for (int e = 0; e < 8; ++e) { ssum[w][c0 + e] = asum[e]; ssq[w][c0 + e] = asq[e]; }
    __syncthreads();
    {
        const int ch0 = tid * 2;
        #pragma unroll
        for (int u = 0; u < 2; ++u) {
            const int ch = ch0 + u;
            float S = ssum[0][ch] + ssum[1][ch] + ssum[2][ch] + ssum[3][ch];
            float Q = ssq[0][ch] + ssq[1][ch] + ssq[2][ch] + ssq[3][ch];
            atomicAdd(&sums2[ch], S);
            atomicAdd(&sqs2[ch], Q);
        }
    }
}

// ---------------------------------------------------------------------------
// Fold BN2 into GEMM2 weights (BN2 finalize fused in):
// sc2/shf2 computed per-thread from raw sums2/sqs2.
// W2eff[c][d] = sign(w2[c][d]) * sc2[d] (bf16)
// b2eff[c] = b2[c] + sum_d sign(w2[c][d]) * shf2[d]
// ---------------------------------------------------------------------------
__global__ void fold_kernel(const float* __restrict__ w2,
                            const float* __restrict__ sums2, const float* __restrict__ sqs2,
                            const float* __restrict__ g2, const float* __restrict__ be2,
                            const float* __restrict__ b2,
                            unsigned short* __restrict__ W2E, float* __restrict__ B2E) {
    __shared__ float red[256];
    const int c = blockIdx.x, tid = threadIdx.x;
    const float inv = 1.f / (float)BT;
    float part = 0.f;
    for (int d = tid; d < DCH; d += 256) {
        float mean = sums2[d] * inv;
        float var = sqs2[d] * inv - mean * mean;
        float sc = g2[d] * rsqrtf(var + EPSB);
        float shf = be2[d] - mean * sc;
        float w = w2[(size_t)c * DCH + d];
        float sgn = signf_(w);
        W2E[(size_t)c * DCH + d] = f2bf(sgn * sc);
        part += sgn * shf;
    }
    red[tid] = part;
    __syncthreads();
    for (int off = 128; off > 0; off >>= 1) {
        if (tid < off) red[tid] += red[tid + off];
        __syncthreads();
    }
    if (tid == 0) B2E[c] = b2[c] + red[0];
}

// ---------------------------------------------------------------------------
extern "C" void kernel_launch(void* const* d_in, const int* in_sizes, int n_in,
                              void* d_out, int out_size, void* d_ws, size_t ws_size,
                              hipStream_t stream) {
    const float* x   = (const float*)d_in[0];
    const float* w1  = (const float*)d_in[1];
    const float* b1  = (const float*)d_in[2];
    const float* a1  = (const float*)d_in[3];
    const float* g1  = (const float*)d_in[4];
    const float* be1 = (const float*)d_in[5];
    const float* wd  = (const float*)d_in[6];
    const float* bd  = (const float*)d_in[7];
    const float* a2  = (const float*)d_in[8];
    const float* g2  = (const float*)d_in[9];
    const float* be2 = (const float*)d_in[10];
    const float* w2  = (const float*)d_in[11];
    const float* b2  = (const float*)d_in[12];
    float* out = (float*)d_out;

    char* ws = (char*)d_ws;
    size_t off = 0;
    auto alloc = [&](size_t bytes) -> void* {
        void* p = ws + off;
        off += (bytes + 255) & ~(size_t)255;
        return p;
    };
    unsigned short* XA  = (unsigned short*)alloc((size_t)BT * CBC * 2);
    unsigned short* Y   = (unsigned short*)alloc((size_t)BT * DCH * 2);
    unsigned short* Z   = (unsigned short*)alloc((size_t)BT * DCH * 2);
    unsigned short* W1S = (unsigned short*)alloc((size_t)NL * DCH * CBC * 2);
    float* WDS          = (float*)alloc((size_t)NL * DCH * KW * 4);
    unsigned short* W2E = (unsigned short*)alloc((size_t)CBC * DCH * 2);
    float* B2E          = (float*)alloc((size_t)CBC * 4);
    // per-layer stat buffers: [sums1|sqs1|sums2|sqs2] x NL x 512, zeroed once
    float* stats = (float*)alloc((size_t)4 * NL * 512 * 4);
    float* sums1 = stats + 0 * NL * 512;
    float* sqs1  = stats + 1 * NL * 512;
    float* sums2 = stats + 2 * NL * 512;
    float* sqs2  = stats + 3 * NL * 512;

    (void)hipMemsetAsync(stats, 0, (size_t)4 * NL * 512 * 4, stream);

    {
        const int NTOT = NL * DCH * CBC + NL * DCH * KW;
        prep_kernel<<<(NTOT + 255) / 256, 256, 0, stream>>>(w1, wd, W1S, WDS);
    }
    transpose_in<<<dim3(TT / 64, CBC / 64, BATCH), 256, 0, stream>>>(x, XA);

    const int NWG1 = (DCH / 128) * (TT / 128) * BATCH;   // 4*32*16 = 2048
    const int NWG2 = (CBC / 128) * (TT / 128) * BATCH;   // 2*32*16 = 1024

    for (int l = 0; l < NL; ++l) {
        // 1x1 conv CB->D + bias + PReLU, fused BN1 stats
        gemm_kernel<CBC, DCH / 128, true, false, true><<<NWG1, 256, 0, stream>>>(
            W1S + (size_t)l * DCH * CBC, XA, b1 + (size_t)l * DCH, a1 + l,
            Y, nullptr, nullptr, sums1 + l * 512, sqs1 + l * 512, DCH);
        // depthwise dilated conv (BN1 finalize+fold fused) + bias + PReLU, fused BN2 stats
        dwconv_kernel<<<dim3(TT / DWT, BATCH), 256, 0, stream>>>(
            Y, sums1 + l * 512, sqs1 + l * 512, g1 + (size_t)l * DCH, be1 + (size_t)l * DCH,
            WDS + (size_t)l * DCH * KW, bd + (size_t)l * DCH, a2 + l, 1 << l,
            Z, sums2 + l * 512, sqs2 + l * 512);
        // fold BN2 (finalize fused) into GEMM2 weights
        fold_kernel<<<CBC, 256, 0, stream>>>(w2 + (size_t)l * CBC * DCH,
                                             sums2 + l * 512, sqs2 + l * 512,
                                             g2 + (size_t)l * DCH, be2 + (size_t)l * DCH,
                                             b2 + (size_t)l * CBC, W2E, B2E);
        // 1x1 conv D->CB (+ residual & fp32 [B][CB][T] on final layer)
        if (l < NL - 1) {
            gemm_kernel<DCH, CBC / 128, false, false, false><<<NWG2, 256, 0, stream>>>(
                W2E, Z, B2E, nullptr, XA, nullptr, nullptr, nullptr, nullptr, CBC);
        } else {
            gemm_kernel<DCH, CBC / 128, false, true, false><<<NWG2, 256, 0, stream>>>(
                W2E, Z, B2E, nullptr, nullptr, out, x, nullptr, nullptr, CBC);
        }
    }
}

// Round 5
// 617.158 us; speedup vs baseline: 1.5314x; 1.5314x over previous
//
#include <hip/hip_runtime.h>
#include <stdint.h>
#include <stddef.h>

#define NL   4
#define CBC  256
#define DCH  512
#define KW   3
#define BATCH 16
#define TT   4096
#define BT   (BATCH*TT)
#define EPSB 1e-5f

typedef __bf16 bf16_t;
typedef __attribute__((ext_vector_type(8))) __bf16 bf16x8;
typedef __attribute__((ext_vector_type(4))) float f32x4;
typedef __attribute__((ext_vector_type(8))) unsigned short us8;
typedef __attribute__((ext_vector_type(4))) unsigned short us4;

static __device__ __forceinline__ unsigned short f2bf(float f) {
    union { float f; uint32_t u; } v; v.f = f;
    uint32_t u = v.u;
    u += 0x7FFFu + ((u >> 16) & 1u);   // RNE
    return (unsigned short)(u >> 16);
}
static __device__ __forceinline__ float bf2f(unsigned short b) {
    union { uint32_t u; float f; } v; v.u = ((uint32_t)b) << 16;
    return v.f;
}
static __device__ __forceinline__ bf16x8 as_bf16x8(us8 u) {
    return __builtin_bit_cast(bf16x8, u);
}
static __device__ __forceinline__ float signf_(float w) {
    return (w > 0.f) ? 1.f : ((w < 0.f) ? -1.f : 0.f);
}

typedef __attribute__((address_space(1))) void as1_void;
typedef __attribute__((address_space(3))) void as3_void;
static __device__ __forceinline__ void gload_lds16(const unsigned short* g, unsigned short* l) {
    // 16B per lane, wave-uniform LDS base + lane*16 (guide §5: width=16 verified m97)
    __builtin_amdgcn_global_load_lds((as1_void*)g, (as3_void*)l, 16, 0, 0);
}

// ---------------------------------------------------------------------------
// Weight prep: sign(w1) -> bf16 [L][D][CB]; sign(wd) -> f32 [L][D][3]
// ---------------------------------------------------------------------------
__global__ void prep_kernel(const float* __restrict__ w1, const float* __restrict__ wd,
                            unsigned short* __restrict__ W1S, float* __restrict__ WDS) {
    const int NW1 = NL * DCH * CBC;
    const int NWD = NL * DCH * KW;
    int idx = blockIdx.x * 256 + threadIdx.x;
    if (idx < NW1) {
        W1S[idx] = f2bf(signf_(w1[idx]));
    } else if (idx < NW1 + NWD) {
        int j = idx - NW1;
        WDS[j] = signf_(wd[j]);
    }
}

// ---------------------------------------------------------------------------
// Input transpose: x [B][CB][T] f32  ->  XA [B*T][CB] bf16
// ---------------------------------------------------------------------------
__global__ void transpose_in(const float* __restrict__ x, unsigned short* __restrict__ XA) {
    __shared__ unsigned short tile[64][72];
    const int t0 = blockIdx.x * 64, c0 = blockIdx.y * 64, b = blockIdx.z;
    const int tid = threadIdx.x;
    {
        const int cl = tid >> 2;
        const int tl = (tid & 3) * 16;
        const float* src = x + ((size_t)(b * CBC + c0 + cl)) * TT + t0 + tl;
        #pragma unroll
        for (int u = 0; u < 16; u += 4) {
            float4 f = *(const float4*)(src + u);
            tile[cl][tl + u + 0] = f2bf(f.x);
            tile[cl][tl + u + 1] = f2bf(f.y);
            tile[cl][tl + u + 2] = f2bf(f.z);
            tile[cl][tl + u + 3] = f2bf(f.w);
        }
    }
    __syncthreads();
    {
        const int tr = tid >> 2;
        const int cc = (tid & 3) * 16;
        us8 o0, o1;
        #pragma unroll
        for (int e = 0; e < 8; ++e) { o0[e] = tile[cc + e][tr]; o1[e] = tile[cc + 8 + e][tr]; }
        unsigned short* dst = XA + ((size_t)(b * TT + t0 + tr)) * CBC + c0 + cc;
        *(us8*)dst = o0;
        *(us8*)(dst + 8) = o1;
    }
}

// ---------------------------------------------------------------------------
// GEMM: out[n][m] = sum_k A[m][k] * B[n][k] (+bias, optional PReLU)
// 128x128 tile, BK=32. Catalog-verified 2-phase double-buffer (T3 minimum
// recipe, m248v2): per iter {STAGE(next tile) -> ds_read(cur) -> MFMA ->
// vmcnt(0) -> s_barrier}. sched_barrier(0) after every waitcnt/barrier pins
// the schedule (rule #18). LDS XOR swizzle both-sides (rule #21).
// Grid: 1D, bijective XCD-chunked swizzle, m-tiles innermost (L2 B-reuse).
// UNCHANGED from round 3 (correctness- and perf-verified).
// ---------------------------------------------------------------------------
template<int K, int NMT, bool PRELU, bool FINAL, bool STATS>
__global__ __launch_bounds__(256, 4)
void gemm_kernel(const unsigned short* __restrict__ A,
                 const unsigned short* __restrict__ Bact,
                 const float* __restrict__ bias,
                 const float* __restrict__ aptr,
                 unsigned short* __restrict__ Obf,
                 float* __restrict__ Ofin,
                 const float* __restrict__ resid,
                 float* __restrict__ sums, float* __restrict__ sqs,
                 int M) {
    __shared__ union {
        unsigned short stage[2][4][2048];    // [buf][A0,A1,B0,B1][64 rows x 32] = 32KB
        unsigned short sout[128 * 136];      // epilogue transpose (34KB)
    } sm;
    __shared__ float sstat[2][4][64];        // [sum/sq][wave][ch_local]

    const int tid = threadIdx.x;

    // bijective XCD-chunked swizzle (nwg % 8 == 0 always here, m204)
    const int nwg = NMT * (TT / 128) * BATCH;
    const int orig = blockIdx.x;
    const int logical = (orig & 7) * (nwg >> 3) + (orig >> 3);
    const int mt = logical % NMT;            // m-tile innermost -> same-XCD B reuse
    const int rest = logical / NMT;
    const int tt = rest & 31;                // TT/128 = 32 t-tiles
    const int bz = rest >> 5;
    const int t0 = tt * 128;
    const int m0 = mt * 128;
    const size_t n0 = (size_t)bz * TT + t0;

    const int lane = tid & 63;
    const int w    = tid >> 6;
    const int wm = w & 1, wn = w >> 1;
    const int l16 = lane & 15, q = lane >> 4;

    // staging: thread tid covers half-tile row tid>>2, swizzled 16B chunk
    const int rS = tid >> 2;
    const int cS = ((tid & 3) ^ ((tid >> 3) & 3)) * 8;   // chunk ^ ((row>>1)&3)
    const unsigned short* gA0 = A + (size_t)(m0 + rS) * K + cS;
    const unsigned short* gA1 = A + (size_t)(m0 + 64 + rS) * K + cS;
    const unsigned short* gB0 = Bact + (n0 + rS) * K + cS;
    const unsigned short* gB1 = Bact + (n0 + 64 + rS) * K + cS;
    const int wofs = w << 9;                  // per-wave 512-short (1KB) slice

    auto STAGE = [&](int step, int buf) {
        const int k0 = step * 32;
        unsigned short* sb = &sm.stage[buf][0][0];
        gload_lds16(gA0 + k0, sb + 0 * 2048 + wofs);
        gload_lds16(gA1 + k0, sb + 1 * 2048 + wofs);
        gload_lds16(gB0 + k0, sb + 2 * 2048 + wofs);
        gload_lds16(gB1 + k0, sb + 3 * 2048 + wofs);
    };

    f32x4 acc[4][4];
    #pragma unroll
    for (int i = 0; i < 4; ++i)
        #pragma unroll
        for (int j = 0; j < 4; ++j)
            acc[i][j] = (f32x4){0.f, 0.f, 0.f, 0.f};

    // read-side swizzle: same XOR as write side; ((i*16+l16)>>1)&3 == (l16>>1)&3
    const int csw = (q ^ ((l16 >> 1) & 3)) << 3;

    constexpr int NK = K / 32;
    // prologue: stage tile 0, publish
    STAGE(0, 0);
    asm volatile("s_waitcnt vmcnt(0)" ::: "memory");
    __builtin_amdgcn_s_barrier();
    __builtin_amdgcn_sched_barrier(0);

    #pragma unroll
    for (int k = 0; k < NK; ++k) {
        const int cur = k & 1;
        // issue next-tile loads FIRST (latency hides under compute below).
        if (k + 1 < NK) STAGE(k + 1, cur ^ 1);
        const unsigned short* sb = &sm.stage[cur][0][0];
        bf16x8 af[4], bfv[4];
        #pragma unroll
        for (int i = 0; i < 4; ++i)
            af[i] = as_bf16x8(*(const us8*)(sb + wm * 2048 + (i * 16 + l16) * 32 + csw));
        #pragma unroll
        for (int j = 0; j < 4; ++j)
            bfv[j] = as_bf16x8(*(const us8*)(sb + (2 + wn) * 2048 + (j * 16 + l16) * 32 + csw));
        #pragma unroll
        for (int i = 0; i < 4; ++i)
            #pragma unroll
            for (int j = 0; j < 4; ++j)
                acc[i][j] = __builtin_amdgcn_mfma_f32_16x16x32_bf16(af[i], bfv[j], acc[i][j], 0, 0, 0);
        // publish next tile: own loads landed, then barrier => all waves' landed
        if (k + 1 < NK) {
            asm volatile("s_waitcnt vmcnt(0)" ::: "memory");
            __builtin_amdgcn_sched_barrier(0);
        }
        __builtin_amdgcn_s_barrier();
        __builtin_amdgcn_sched_barrier(0);
    }

    float alpha = 0.f;
    if constexpr (PRELU) alpha = aptr[0];

    if constexpr (FINAL) {
        #pragma unroll
        for (int i = 0; i < 4; ++i) {
            const int m_l = wm * 64 + i * 16 + q * 4;
            float bia[4];
            #pragma unroll
            for (int rg = 0; rg < 4; ++rg) bia[rg] = bias[m0 + m_l + rg];
            #pragma unroll
            for (int j = 0; j < 4; ++j) {
                const int n_l = wn * 64 + j * 16 + l16;
                const int t = t0 + n_l;
                #pragma unroll
                for (int rg = 0; rg < 4; ++rg) {
                    float v = acc[i][j][rg] + bia[rg];
                    size_t oidx = ((size_t)(bz * CBC + m0 + m_l + rg)) * TT + t;
                    Ofin[oidx] = v + resid[oidx];
                }
            }
        }
    } else {
        #pragma unroll
        for (int i = 0; i < 4; ++i) {
            const int m_l = wm * 64 + i * 16 + q * 4;
            float bia[4];
            #pragma unroll
            for (int rg = 0; rg < 4; ++rg) bia[rg] = bias[m0 + m_l + rg];
            #pragma unroll
            for (int j = 0; j < 4; ++j) {
                const int n_l = wn * 64 + j * 16 + l16;
                us4 pkv;
                #pragma unroll
                for (int rg = 0; rg < 4; ++rg) {
                    float v = acc[i][j][rg] + bia[rg];
                    if (PRELU) v = (v >= 0.f) ? v : alpha * v;
                    pkv[rg] = f2bf(v);
                }
                *(us4*)&sm.sout[n_l * 136 + m_l] = pkv;
            }
            if constexpr (STATS) {
                #pragma unroll
                for (int rg = 0; rg < 4; ++rg) {
                    float sv = 0.f, sq2 = 0.f;
                    #pragma unroll
                    for (int j = 0; j < 4; ++j) {
                        float v = acc[i][j][rg] + bia[rg];
                        if (PRELU) v = (v >= 0.f) ? v : alpha * v;
                        sv += v; sq2 += v * v;
                    }
                    #pragma unroll
                    for (int msk = 1; msk < 16; msk <<= 1) {
                        sv  += __shfl_xor(sv,  msk, 64);
                        sq2 += __shfl_xor(sq2, msk, 64);
                    }
                    if (l16 == 0) {
                        const int cl = i * 16 + q * 4 + rg;   // channel local to wm
                        sstat[0][w][cl] = sv;
                        sstat[1][w][cl] = sq2;
                    }
                }
            }
        }
        __syncthreads();
        const int rr = tid >> 4;
        const int c8 = (tid & 15) * 8;
        #pragma unroll
        for (int p = 0; p < 8; ++p) {
            const int n_l = p * 16 + rr;
            us8 v = *(const us8*)&sm.sout[n_l * 136 + c8];
            *(us8*)(Obf + (n0 + n_l) * M + m0 + c8) = v;
        }
        if constexpr (STATS) {
            if (tid < 128) {
                const int wmc = tid >> 6, cl = tid & 63;
                float S = sstat[0][wmc][cl] + sstat[0][wmc + 2][cl];
                float Q = sstat[1][wmc][cl] + sstat[1][wmc + 2][cl];
                atomicAdd(&sums[m0 + tid], S);
                atomicAdd(&sqs[m0 + tid], Q);
            }
        }
    }
}

// ---------------------------------------------------------------------------
// Depthwise dilated causal conv + bias + PReLU, fused Z-stats.
// ROUND-3 BODY (verified 78us, 82/74MB traffic) with ONE lever: channel-
// split grid. grid = (TT/64, 2, BATCH); block handles 64 t-rows x one
// 256-channel half; each lane owns 4 channels (us4, 8B/lane coalesced).
// 2048 blocks x 4 waves = 8192 waves = machine exactly full (round-3 grid
// half-filled it -> 30% occupancy was the measured limiter).
// Channel halves are DISJOINT: no read duplication (unlike round-4's t-split,
// which inflated FETCH by up to 50%); Z half-rows split at a 512B boundary
// -> no partial-line writes.
// BN1 finalize FUSED (correctness proven in round 4): per-lane scale/shift
// from raw sums1/sqs1.
// ---------------------------------------------------------------------------
__global__ __launch_bounds__(256)
void dwconv_kernel(const unsigned short* __restrict__ Y,
                   const float* __restrict__ sums1, const float* __restrict__ sqs1,
                   const float* __restrict__ g1, const float* __restrict__ be1,
                   const float* __restrict__ wds, const float* __restrict__ bd,
                   const float* __restrict__ a2p, int dil,
                   unsigned short* __restrict__ Z,
                   float* __restrict__ sums2, float* __restrict__ sqs2) {
    __shared__ float ssum[4][256];
    __shared__ float ssq[4][256];
    const int b = blockIdx.z;
    const int half = blockIdx.y;
    const int t0 = blockIdx.x * 64;
    const int tid = threadIdx.x;
    const int w = tid >> 6;
    const int lane = tid & 63;
    const int cloc = lane * 4;            // channel local to this half
    const int c0 = half * 256 + cloc;     // global channel base (4 channels)
    const float alpha = a2p[0];

    // fused BN1 finalize (per-lane, 4 channels) + weights
    float s4[4], sh4[4], wv0[4], wv1[4], wv2[4], bb4[4];
    const float inv = 1.f / (float)BT;
    #pragma unroll
    for (int e = 0; e < 4; ++e) {
        const int d = c0 + e;
        float mean = sums1[d] * inv;
        float var = sqs1[d] * inv - mean * mean;
        float sc = g1[d] * rsqrtf(var + EPSB);
        s4[e] = sc;
        sh4[e] = be1[d] - mean * sc;
        wv0[e] = wds[d * 3 + 0]; wv1[e] = wds[d * 3 + 1]; wv2[e] = wds[d * 3 + 2];
        bb4[e] = bd[d];
    }

    float asum[4], asq[4];
    #pragma unroll
    for (int e = 0; e < 4; ++e) { asum[e] = 0.f; asq[e] = 0.f; }

    for (int it = 0; it < 16; ++it) {
        const int t = t0 + it * 4 + w;
        const size_t base = ((size_t)b * TT + t) * DCH + c0;
        float acc[4];
        {
            us4 y0 = *(const us4*)&Y[base];
            #pragma unroll
            for (int e = 0; e < 4; ++e)
                acc[e] = wv2[e] * (s4[e] * bf2f(y0[e]) + sh4[e]) + bb4[e];
        }
        if (t >= dil) {
            us4 y1 = *(const us4*)&Y[base - (size_t)dil * DCH];
            #pragma unroll
            for (int e = 0; e < 4; ++e)
                acc[e] += wv1[e] * (s4[e] * bf2f(y1[e]) + sh4[e]);
        }
        if (t >= 2 * dil) {
            us4 y2 = *(const us4*)&Y[base - (size_t)(2 * dil) * DCH];
            #pragma unroll
            for (int e = 0; e < 4; ++e)
                acc[e] += wv0[e] * (s4[e] * bf2f(y2[e]) + sh4[e]);
        }
        us4 o;
        #pragma unroll
        for (int e = 0; e < 4; ++e) {
            float v = acc[e];
            v = (v >= 0.f) ? v : alpha * v;
            asum[e] += v; asq[e] += v * v;
            o[e] = f2bf(v);
        }
        *(us4*)&Z[base] = o;
    }

    #pragma unroll
    for (int e = 0; e < 4; ++e) { ssum[w][cloc + e] = asum[e]; ssq[w][cloc + e] = asq[e]; }
    __syncthreads();
    {
        const int ch = tid;   // 0..255 (one channel per thread)
        float S = ssum[0][ch] + ssum[1][ch] + ssum[2][ch] + ssum[3][ch];
        float Q = ssq[0][ch] + ssq[1][ch] + ssq[2][ch] + ssq[3][ch];
        atomicAdd(&sums2[half * 256 + ch], S);
        atomicAdd(&sqs2[half * 256 + ch], Q);
    }
}

// ---------------------------------------------------------------------------
// Fold BN2 into GEMM2 weights (BN2 finalize fused in):
// sc2/shf2 computed per-thread from raw sums2/sqs2.
// W2eff[c][d] = sign(w2[c][d]) * sc2[d] (bf16)
// b2eff[c] = b2[c] + sum_d sign(w2[c][d]) * shf2[d]
// ---------------------------------------------------------------------------
__global__ void fold_kernel(const float* __restrict__ w2,
                            const float* __restrict__ sums2, const float* __restrict__ sqs2,
                            const float* __restrict__ g2, const float* __restrict__ be2,
                            const float* __restrict__ b2,
                            unsigned short* __restrict__ W2E, float* __restrict__ B2E) {
    __shared__ float red[256];
    const int c = blockIdx.x, tid = threadIdx.x;
    const float inv = 1.f / (float)BT;
    float part = 0.f;
    for (int d = tid; d < DCH; d += 256) {
        float mean = sums2[d] * inv;
        float var = sqs2[d] * inv - mean * mean;
        float sc = g2[d] * rsqrtf(var + EPSB);
        float shf = be2[d] - mean * sc;
        float w = w2[(size_t)c * DCH + d];
        float sgn = signf_(w);
        W2E[(size_t)c * DCH + d] = f2bf(sgn * sc);
        part += sgn * shf;
    }
    red[tid] = part;
    __syncthreads();
    for (int off = 128; off > 0; off >>= 1) {
        if (tid < off) red[tid] += red[tid + off];
        __syncthreads();
    }
    if (tid == 0) B2E[c] = b2[c] + red[0];
}

// ---------------------------------------------------------------------------
extern "C" void kernel_launch(void* const* d_in, const int* in_sizes, int n_in,
                              void* d_out, int out_size, void* d_ws, size_t ws_size,
                              hipStream_t stream) {
    const float* x   = (const float*)d_in[0];
    const float* w1  = (const float*)d_in[1];
    const float* b1  = (const float*)d_in[2];
    const float* a1  = (const float*)d_in[3];
    const float* g1  = (const float*)d_in[4];
    const float* be1 = (const float*)d_in[5];
    const float* wd  = (const float*)d_in[6];
    const float* bd  = (const float*)d_in[7];
    const float* a2  = (const float*)d_in[8];
    const float* g2  = (const float*)d_in[9];
    const float* be2 = (const float*)d_in[10];
    const float* w2  = (const float*)d_in[11];
    const float* b2  = (const float*)d_in[12];
    float* out = (float*)d_out;

    char* ws = (char*)d_ws;
    size_t off = 0;
    auto alloc = [&](size_t bytes) -> void* {
        void* p = ws + off;
        off += (bytes + 255) & ~(size_t)255;
        return p;
    };
    unsigned short* XA  = (unsigned short*)alloc((size_t)BT * CBC * 2);
    unsigned short* Y   = (unsigned short*)alloc((size_t)BT * DCH * 2);
    unsigned short* Z   = (unsigned short*)alloc((size_t)BT * DCH * 2);
    unsigned short* W1S = (unsigned short*)alloc((size_t)NL * DCH * CBC * 2);
    float* WDS          = (float*)alloc((size_t)NL * DCH * KW * 4);
    unsigned short* W2E = (unsigned short*)alloc((size_t)CBC * DCH * 2);
    float* B2E          = (float*)alloc((size_t)CBC * 4);
    // per-layer stat buffers: [sums1|sqs1|sums2|sqs2] x NL x 512, zeroed once
    float* stats = (float*)alloc((size_t)4 * NL * 512 * 4);
    float* sums1 = stats + 0 * NL * 512;
    float* sqs1  = stats + 1 * NL * 512;
    float* sums2 = stats + 2 * NL * 512;
    float* sqs2  = stats + 3 * NL * 512;

    (void)hipMemsetAsync(stats, 0, (size_t)4 * NL * 512 * 4, stream);

    {
        const int NTOT = NL * DCH * CBC + NL * DCH * KW;
        prep_kernel<<<(NTOT + 255) / 256, 256, 0, stream>>>(w1, wd, W1S, WDS);
    }
    transpose_in<<<dim3(TT / 64, CBC / 64, BATCH), 256, 0, stream>>>(x, XA);

    const int NWG1 = (DCH / 128) * (TT / 128) * BATCH;   // 4*32*16 = 2048
    const int NWG2 = (CBC / 128) * (TT / 128) * BATCH;   // 2*32*16 = 1024

    for (int l = 0; l < NL; ++l) {
        // 1x1 conv CB->D + bias + PReLU, fused BN1 stats
        gemm_kernel<CBC, DCH / 128, true, false, true><<<NWG1, 256, 0, stream>>>(
            W1S + (size_t)l * DCH * CBC, XA, b1 + (size_t)l * DCH, a1 + l,
            Y, nullptr, nullptr, sums1 + l * 512, sqs1 + l * 512, DCH);
        // depthwise dilated conv (BN1 finalize fused) + bias + PReLU, fused BN2 stats
        dwconv_kernel<<<dim3(TT / 64, 2, BATCH), 256, 0, stream>>>(
            Y, sums1 + l * 512, sqs1 + l * 512, g1 + (size_t)l * DCH, be1 + (size_t)l * DCH,
            WDS + (size_t)l * DCH * KW, bd + (size_t)l * DCH, a2 + l, 1 << l,
            Z, sums2 + l * 512, sqs2 + l * 512);
        // fold BN2 (finalize fused) into GEMM2 weights
        fold_kernel<<<CBC, 256, 0, stream>>>(w2 + (size_t)l * CBC * DCH,
                                             sums2 + l * 512, sqs2 + l * 512,
                                             g2 + (size_t)l * DCH, be2 + (size_t)l * DCH,
                                             b2 + (size_t)l * CBC, W2E, B2E);
        // 1x1 conv D->CB (+ residual & fp32 [B][CB][T] on final layer)
        if (l < NL - 1) {
            gemm_kernel<DCH, CBC / 128, false, false, false><<<NWG2, 256, 0, stream>>>(
                W2E, Z, B2E, nullptr, XA, nullptr, nullptr, nullptr, nullptr, CBC);
        } else {
            gemm_kernel<DCH, CBC / 128, false, true, false><<<NWG2, 256, 0, stream>>>(
                W2E, Z, B2E, nullptr, nullptr, out, x, nullptr, nullptr, CBC);
        }
    }
}

// Round 6
// 581.252 us; speedup vs baseline: 1.6260x; 1.0618x over previous
//
#include <hip/hip_runtime.h>
#include <stdint.h>
#include <stddef.h>

#define NL   4
#define CBC  256
#define DCH  512
#define KW   3
#define BATCH 16
#define TT   4096
#define BT   (BATCH*TT)
#define EPSB 1e-5f

typedef __bf16 bf16_t;
typedef __attribute__((ext_vector_type(8))) __bf16 bf16x8;
typedef __attribute__((ext_vector_type(4))) float f32x4;
typedef __attribute__((ext_vector_type(8))) unsigned short us8;
typedef __attribute__((ext_vector_type(4))) unsigned short us4;

static __device__ __forceinline__ unsigned short f2bf(float f) {
    union { float f; uint32_t u; } v; v.f = f;
    uint32_t u = v.u;
    u += 0x7FFFu + ((u >> 16) & 1u);   // RNE
    return (unsigned short)(u >> 16);
}
static __device__ __forceinline__ float bf2f(unsigned short b) {
    union { uint32_t u; float f; } v; v.u = ((uint32_t)b) << 16;
    return v.f;
}
static __device__ __forceinline__ bf16x8 as_bf16x8(us8 u) {
    return __builtin_bit_cast(bf16x8, u);
}
static __device__ __forceinline__ float signf_(float w) {
    return (w > 0.f) ? 1.f : ((w < 0.f) ? -1.f : 0.f);
}

typedef __attribute__((address_space(1))) void as1_void;
typedef __attribute__((address_space(3))) void as3_void;
static __device__ __forceinline__ void gload_lds16(const unsigned short* g, unsigned short* l) {
    // 16B per lane, wave-uniform LDS base + lane*16 (guide §5: width=16 verified m97)
    __builtin_amdgcn_global_load_lds((as1_void*)g, (as3_void*)l, 16, 0, 0);
}

// ---------------------------------------------------------------------------
// Weight prep: sign(w1) -> bf16 [L][D][CB]; sign(wd) -> f32 [L][D][3]
// ---------------------------------------------------------------------------
__global__ void prep_kernel(const float* __restrict__ w1, const float* __restrict__ wd,
                            unsigned short* __restrict__ W1S, float* __restrict__ WDS) {
    const int NW1 = NL * DCH * CBC;
    const int NWD = NL * DCH * KW;
    int idx = blockIdx.x * 256 + threadIdx.x;
    if (idx < NW1) {
        W1S[idx] = f2bf(signf_(w1[idx]));
    } else if (idx < NW1 + NWD) {
        int j = idx - NW1;
        WDS[j] = signf_(wd[j]);
    }
}

// ---------------------------------------------------------------------------
// Input transpose: x [B][CB][T] f32  ->  XA [B*T][CB] bf16
// ---------------------------------------------------------------------------
__global__ void transpose_in(const float* __restrict__ x, unsigned short* __restrict__ XA) {
    __shared__ unsigned short tile[64][72];
    const int t0 = blockIdx.x * 64, c0 = blockIdx.y * 64, b = blockIdx.z;
    const int tid = threadIdx.x;
    {
        const int cl = tid >> 2;
        const int tl = (tid & 3) * 16;
        const float* src = x + ((size_t)(b * CBC + c0 + cl)) * TT + t0 + tl;
        #pragma unroll
        for (int u = 0; u < 16; u += 4) {
            float4 f = *(const float4*)(src + u);
            tile[cl][tl + u + 0] = f2bf(f.x);
            tile[cl][tl + u + 1] = f2bf(f.y);
            tile[cl][tl + u + 2] = f2bf(f.z);
            tile[cl][tl + u + 3] = f2bf(f.w);
        }
    }
    __syncthreads();
    {
        const int tr = tid >> 2;
        const int cc = (tid & 3) * 16;
        us8 o0, o1;
        #pragma unroll
        for (int e = 0; e < 8; ++e) { o0[e] = tile[cc + e][tr]; o1[e] = tile[cc + 8 + e][tr]; }
        unsigned short* dst = XA + ((size_t)(b * TT + t0 + tr)) * CBC + c0 + cc;
        *(us8*)dst = o0;
        *(us8*)(dst + 8) = o1;
    }
}

// ---------------------------------------------------------------------------
// GEMM: out[n][m] = sum_k A[m][k] * B[n][k] (+bias, optional PReLU)
// 128x128 tile, BK=32. Catalog-verified 2-phase double-buffer (T3 minimum
// recipe, m248v2): per iter {STAGE(next tile) -> ds_read(cur) -> MFMA ->
// vmcnt(0) -> s_barrier}. sched_barrier(0) after every waitcnt/barrier pins
// the schedule (rule #18). LDS XOR swizzle both-sides (rule #21).
// Grid: 1D, bijective XCD-chunked swizzle, m-tiles innermost (L2 B-reuse).
// UNCHANGED from round 3 (correctness- and perf-verified).
// ---------------------------------------------------------------------------
template<int K, int NMT, bool PRELU, bool FINAL, bool STATS>
__global__ __launch_bounds__(256, 4)
void gemm_kernel(const unsigned short* __restrict__ A,
                 const unsigned short* __restrict__ Bact,
                 const float* __restrict__ bias,
                 const float* __restrict__ aptr,
                 unsigned short* __restrict__ Obf,
                 float* __restrict__ Ofin,
                 const float* __restrict__ resid,
                 float* __restrict__ sums, float* __restrict__ sqs,
                 int M) {
    __shared__ union {
        unsigned short stage[2][4][2048];    // [buf][A0,A1,B0,B1][64 rows x 32] = 32KB
        unsigned short sout[128 * 136];      // epilogue transpose (34KB)
    } sm;
    __shared__ float sstat[2][4][64];        // [sum/sq][wave][ch_local]

    const int tid = threadIdx.x;

    // bijective XCD-chunked swizzle (nwg % 8 == 0 always here, m204)
    const int nwg = NMT * (TT / 128) * BATCH;
    const int orig = blockIdx.x;
    const int logical = (orig & 7) * (nwg >> 3) + (orig >> 3);
    const int mt = logical % NMT;            // m-tile innermost -> same-XCD B reuse
    const int rest = logical / NMT;
    const int tt = rest & 31;                // TT/128 = 32 t-tiles
    const int bz = rest >> 5;
    const int t0 = tt * 128;
    const int m0 = mt * 128;
    const size_t n0 = (size_t)bz * TT + t0;

    const int lane = tid & 63;
    const int w    = tid >> 6;
    const int wm = w & 1, wn = w >> 1;
    const int l16 = lane & 15, q = lane >> 4;

    // staging: thread tid covers half-tile row tid>>2, swizzled 16B chunk
    const int rS = tid >> 2;
    const int cS = ((tid & 3) ^ ((tid >> 3) & 3)) * 8;   // chunk ^ ((row>>1)&3)
    const unsigned short* gA0 = A + (size_t)(m0 + rS) * K + cS;
    const unsigned short* gA1 = A + (size_t)(m0 + 64 + rS) * K + cS;
    const unsigned short* gB0 = Bact + (n0 + rS) * K + cS;
    const unsigned short* gB1 = Bact + (n0 + 64 + rS) * K + cS;
    const int wofs = w << 9;                  // per-wave 512-short (1KB) slice

    auto STAGE = [&](int step, int buf) {
        const int k0 = step * 32;
        unsigned short* sb = &sm.stage[buf][0][0];
        gload_lds16(gA0 + k0, sb + 0 * 2048 + wofs);
        gload_lds16(gA1 + k0, sb + 1 * 2048 + wofs);
        gload_lds16(gB0 + k0, sb + 2 * 2048 + wofs);
        gload_lds16(gB1 + k0, sb + 3 * 2048 + wofs);
    };

    f32x4 acc[4][4];
    #pragma unroll
    for (int i = 0; i < 4; ++i)
        #pragma unroll
        for (int j = 0; j < 4; ++j)
            acc[i][j] = (f32x4){0.f, 0.f, 0.f, 0.f};

    // read-side swizzle: same XOR as write side; ((i*16+l16)>>1)&3 == (l16>>1)&3
    const int csw = (q ^ ((l16 >> 1) & 3)) << 3;

    constexpr int NK = K / 32;
    // prologue: stage tile 0, publish
    STAGE(0, 0);
    asm volatile("s_waitcnt vmcnt(0)" ::: "memory");
    __builtin_amdgcn_s_barrier();
    __builtin_amdgcn_sched_barrier(0);

    #pragma unroll
    for (int k = 0; k < NK; ++k) {
        const int cur = k & 1;
        // issue next-tile loads FIRST (latency hides under compute below).
        if (k + 1 < NK) STAGE(k + 1, cur ^ 1);
        const unsigned short* sb = &sm.stage[cur][0][0];
        bf16x8 af[4], bfv[4];
        #pragma unroll
        for (int i = 0; i < 4; ++i)
            af[i] = as_bf16x8(*(const us8*)(sb + wm * 2048 + (i * 16 + l16) * 32 + csw));
        #pragma unroll
        for (int j = 0; j < 4; ++j)
            bfv[j] = as_bf16x8(*(const us8*)(sb + (2 + wn) * 2048 + (j * 16 + l16) * 32 + csw));
        #pragma unroll
        for (int i = 0; i < 4; ++i)
            #pragma unroll
            for (int j = 0; j < 4; ++j)
                acc[i][j] = __builtin_amdgcn_mfma_f32_16x16x32_bf16(af[i], bfv[j], acc[i][j], 0, 0, 0);
        // publish next tile: own loads landed, then barrier => all waves' landed
        if (k + 1 < NK) {
            asm volatile("s_waitcnt vmcnt(0)" ::: "memory");
            __builtin_amdgcn_sched_barrier(0);
        }
        __builtin_amdgcn_s_barrier();
        __builtin_amdgcn_sched_barrier(0);
    }

    float alpha = 0.f;
    if constexpr (PRELU) alpha = aptr[0];

    if constexpr (FINAL) {
        #pragma unroll
        for (int i = 0; i < 4; ++i) {
            const int m_l = wm * 64 + i * 16 + q * 4;
            float bia[4];
            #pragma unroll
            for (int rg = 0; rg < 4; ++rg) bia[rg] = bias[m0 + m_l + rg];
            #pragma unroll
            for (int j = 0; j < 4; ++j) {
                const int n_l = wn * 64 + j * 16 + l16;
                const int t = t0 + n_l;
                #pragma unroll
                for (int rg = 0; rg < 4; ++rg) {
                    float v = acc[i][j][rg] + bia[rg];
                    size_t oidx = ((size_t)(bz * CBC + m0 + m_l + rg)) * TT + t;
                    Ofin[oidx] = v + resid[oidx];
                }
            }
        }
    } else {
        #pragma unroll
        for (int i = 0; i < 4; ++i) {
            const int m_l = wm * 64 + i * 16 + q * 4;
            float bia[4];
            #pragma unroll
            for (int rg = 0; rg < 4; ++rg) bia[rg] = bias[m0 + m_l + rg];
            #pragma unroll
            for (int j = 0; j < 4; ++j) {
                const int n_l = wn * 64 + j * 16 + l16;
                us4 pkv;
                #pragma unroll
                for (int rg = 0; rg < 4; ++rg) {
                    float v = acc[i][j][rg] + bia[rg];
                    if (PRELU) v = (v >= 0.f) ? v : alpha * v;
                    pkv[rg] = f2bf(v);
                }
                *(us4*)&sm.sout[n_l * 136 + m_l] = pkv;
            }
            if constexpr (STATS) {
                #pragma unroll
                for (int rg = 0; rg < 4; ++rg) {
                    float sv = 0.f, sq2 = 0.f;
                    #pragma unroll
                    for (int j = 0; j < 4; ++j) {
                        float v = acc[i][j][rg] + bia[rg];
                        if (PRELU) v = (v >= 0.f) ? v : alpha * v;
                        sv += v; sq2 += v * v;
                    }
                    #pragma unroll
                    for (int msk = 1; msk < 16; msk <<= 1) {
                        sv  += __shfl_xor(sv,  msk, 64);
                        sq2 += __shfl_xor(sq2, msk, 64);
                    }
                    if (l16 == 0) {
                        const int cl = i * 16 + q * 4 + rg;   // channel local to wm
                        sstat[0][w][cl] = sv;
                        sstat[1][w][cl] = sq2;
                    }
                }
            }
        }
        __syncthreads();
        const int rr = tid >> 4;
        const int c8 = (tid & 15) * 8;
        #pragma unroll
        for (int p = 0; p < 8; ++p) {
            const int n_l = p * 16 + rr;
            us8 v = *(const us8*)&sm.sout[n_l * 136 + c8];
            *(us8*)(Obf + (n0 + n_l) * M + m0 + c8) = v;
        }
        if constexpr (STATS) {
            if (tid < 128) {
                const int wmc = tid >> 6, cl = tid & 63;
                float S = sstat[0][wmc][cl] + sstat[0][wmc + 2][cl];
                float Q = sstat[1][wmc][cl] + sstat[1][wmc + 2][cl];
                atomicAdd(&sums[m0 + tid], S);
                atomicAdd(&sqs[m0 + tid], Q);
            }
        }
    }
}

// ---------------------------------------------------------------------------
// Depthwise dilated causal conv + bias + PReLU, fused Z-stats.
// Round-5 grid (channel-split, verified: occupancy 63%, clean traffic) with
// ONE lever: 16B/lane layout (G13 sweet spot; m13's 6.3TB/s was measured at
// 16B/lane). Each wave covers 2 t-rows x 256 ch: r=lane>>5 picks the row,
// (lane&31)*8 the channels -> us8 loads/stores (two 512B contiguous
// segments per instruction), 8 iters instead of 16 -> VMEM instr count
// halved. Steady blocks (bx>0) use the round-4-PROVEN exact BN1 fold
// (wk in {+-1,0} => Wks = wk*s exact; shall = (w0+w1+w2)*sh + bd);
// block bx==0 keeps the unfolded conditional-tap path.
// grid = (TT/64, 2, BATCH), block 256.
// ---------------------------------------------------------------------------
__global__ __launch_bounds__(256)
void dwconv_kernel(const unsigned short* __restrict__ Y,
                   const float* __restrict__ sums1, const float* __restrict__ sqs1,
                   const float* __restrict__ g1, const float* __restrict__ be1,
                   const float* __restrict__ wds, const float* __restrict__ bd,
                   const float* __restrict__ a2p, int dil,
                   unsigned short* __restrict__ Z,
                   float* __restrict__ sums2, float* __restrict__ sqs2) {
    __shared__ float ssum[4][256];
    __shared__ float ssq[4][256];
    const int b = blockIdx.z;
    const int half = blockIdx.y;
    const int t0 = blockIdx.x * 64;
    const int tid = threadIdx.x;
    const int w = tid >> 6;
    const int lane = tid & 63;
    const int r = lane >> 5;              // row sub-index within wave (0/1)
    const int cl = (lane & 31) * 8;       // channel local to this half
    const int c0 = half * 256 + cl;       // global channel base (8 channels)
    const float alpha = a2p[0];

    // fused BN1 finalize (per-lane, 8 channels) + raw weights
    float s8[8], sh8[8], wv0[8], wv1[8], wv2[8], bb8[8];
    const float inv = 1.f / (float)BT;
    #pragma unroll
    for (int e = 0; e < 8; ++e) {
        const int d = c0 + e;
        float mean = sums1[d] * inv;
        float var = sqs1[d] * inv - mean * mean;
        float sc = g1[d] * rsqrtf(var + EPSB);
        s8[e] = sc;
        sh8[e] = be1[d] - mean * sc;
        wv0[e] = wds[d * 3 + 0]; wv1[e] = wds[d * 3 + 1]; wv2[e] = wds[d * 3 + 2];
        bb8[e] = bd[d];
    }

    float asum[8], asq[8];
    #pragma unroll
    for (int e = 0; e < 8; ++e) { asum[e] = 0.f; asq[e] = 0.f; }

    if (blockIdx.x == 0) {
        // boundary block: conditional taps (t < 2*dil possible), unfolded BN
        for (int it = 0; it < 8; ++it) {
            const int t = it * 8 + 2 * w + r;
            const size_t base = ((size_t)b * TT + t) * DCH + c0;
            float acc[8];
            {
                us8 y0 = *(const us8*)&Y[base];
                #pragma unroll
                for (int e = 0; e < 8; ++e)
                    acc[e] = wv2[e] * (s8[e] * bf2f(y0[e]) + sh8[e]) + bb8[e];
            }
            if (t >= dil) {
                us8 y1 = *(const us8*)&Y[base - (size_t)dil * DCH];
                #pragma unroll
                for (int e = 0; e < 8; ++e)
                    acc[e] += wv1[e] * (s8[e] * bf2f(y1[e]) + sh8[e]);
            }
            if (t >= 2 * dil) {
                us8 y2 = *(const us8*)&Y[base - (size_t)(2 * dil) * DCH];
                #pragma unroll
                for (int e = 0; e < 8; ++e)
                    acc[e] += wv0[e] * (s8[e] * bf2f(y2[e]) + sh8[e]);
            }
            us8 o;
            #pragma unroll
            for (int e = 0; e < 8; ++e) {
                float v = acc[e];
                v = (v >= 0.f) ? v : alpha * v;
                asum[e] += v; asq[e] += v * v;
                o[e] = f2bf(v);
            }
            *(us8*)&Z[base] = o;
        }
    } else {
        // steady blocks: exact BN fold (w = +-1/0), unconditional taps
        float W0s[8], W1s[8], W2s[8], shall[8];
        #pragma unroll
        for (int e = 0; e < 8; ++e) {
            W0s[e] = wv0[e] * s8[e];
            W1s[e] = wv1[e] * s8[e];
            W2s[e] = wv2[e] * s8[e];
            shall[e] = (wv0[e] + wv1[e] + wv2[e]) * sh8[e] + bb8[e];
        }
        const size_t d1 = (size_t)dil * DCH, d2 = 2 * d1;
        for (int it = 0; it < 8; ++it) {
            const int t = t0 + it * 8 + 2 * w + r;
            const size_t base = ((size_t)b * TT + t) * DCH + c0;
            us8 y0 = *(const us8*)&Y[base];
            us8 y1 = *(const us8*)&Y[base - d1];
            us8 y2 = *(const us8*)&Y[base - d2];
            us8 o;
            #pragma unroll
            for (int e = 0; e < 8; ++e) {
                float v = W2s[e] * bf2f(y0[e]) + W1s[e] * bf2f(y1[e])
                        + W0s[e] * bf2f(y2[e]) + shall[e];
                v = (v >= 0.f) ? v : alpha * v;
                asum[e] += v; asq[e] += v * v;
                o[e] = f2bf(v);
            }
            *(us8*)&Z[base] = o;
        }
    }

    // combine the two row-groups (lane l and l+32 hold the same channels)
    #pragma unroll
    for (int e = 0; e < 8; ++e) {
        asum[e] += __shfl_xor(asum[e], 32, 64);
        asq[e]  += __shfl_xor(asq[e], 32, 64);
    }
    if (lane < 32) {
        #pragma unroll
        for (int e = 0; e < 8; ++e) { ssum[w][cl + e] = asum[e]; ssq[w][cl + e] = asq[e]; }
    }
    __syncthreads();
    {
        const int ch = tid;   // 0..255 (one channel per thread, local to half)
        float S = ssum[0][ch] + ssum[1][ch] + ssum[2][ch] + ssum[3][ch];
        float Q = ssq[0][ch] + ssq[1][ch] + ssq[2][ch] + ssq[3][ch];
        atomicAdd(&sums2[half * 256 + ch], S);
        atomicAdd(&sqs2[half * 256 + ch], Q);
    }
}

// ---------------------------------------------------------------------------
// Fold BN2 into GEMM2 weights (BN2 finalize fused in):
// sc2/shf2 computed per-thread from raw sums2/sqs2.
// W2eff[c][d] = sign(w2[c][d]) * sc2[d] (bf16)
// b2eff[c] = b2[c] + sum_d sign(w2[c][d]) * shf2[d]
// ---------------------------------------------------------------------------
__global__ void fold_kernel(const float* __restrict__ w2,
                            const float* __restrict__ sums2, const float* __restrict__ sqs2,
                            const float* __restrict__ g2, const float* __restrict__ be2,
                            const float* __restrict__ b2,
                            unsigned short* __restrict__ W2E, float* __restrict__ B2E) {
    __shared__ float red[256];
    const int c = blockIdx.x, tid = threadIdx.x;
    const float inv = 1.f / (float)BT;
    float part = 0.f;
    for (int d = tid; d < DCH; d += 256) {
        float mean = sums2[d] * inv;
        float var = sqs2[d] * inv - mean * mean;
        float sc = g2[d] * rsqrtf(var + EPSB);
        float shf = be2[d] - mean * sc;
        float w = w2[(size_t)c * DCH + d];
        float sgn = signf_(w);
        W2E[(size_t)c * DCH + d] = f2bf(sgn * sc);
        part += sgn * shf;
    }
    red[tid] = part;
    __syncthreads();
    for (int off = 128; off > 0; off >>= 1) {
        if (tid < off) red[tid] += red[tid + off];
        __syncthreads();
    }
    if (tid == 0) B2E[c] = b2[c] + red[0];
}

// ---------------------------------------------------------------------------
extern "C" void kernel_launch(void* const* d_in, const int* in_sizes, int n_in,
                              void* d_out, int out_size, void* d_ws, size_t ws_size,
                              hipStream_t stream) {
    const float* x   = (const float*)d_in[0];
    const float* w1  = (const float*)d_in[1];
    const float* b1  = (const float*)d_in[2];
    const float* a1  = (const float*)d_in[3];
    const float* g1  = (const float*)d_in[4];
    const float* be1 = (const float*)d_in[5];
    const float* wd  = (const float*)d_in[6];
    const float* bd  = (const float*)d_in[7];
    const float* a2  = (const float*)d_in[8];
    const float* g2  = (const float*)d_in[9];
    const float* be2 = (const float*)d_in[10];
    const float* w2  = (const float*)d_in[11];
    const float* b2  = (const float*)d_in[12];
    float* out = (float*)d_out;

    char* ws = (char*)d_ws;
    size_t off = 0;
    auto alloc = [&](size_t bytes) -> void* {
        void* p = ws + off;
        off += (bytes + 255) & ~(size_t)255;
        return p;
    };
    unsigned short* XA  = (unsigned short*)alloc((size_t)BT * CBC * 2);
    unsigned short* Y   = (unsigned short*)alloc((size_t)BT * DCH * 2);
    unsigned short* Z   = (unsigned short*)alloc((size_t)BT * DCH * 2);
    unsigned short* W1S = (unsigned short*)alloc((size_t)NL * DCH * CBC * 2);
    float* WDS          = (float*)alloc((size_t)NL * DCH * KW * 4);
    unsigned short* W2E = (unsigned short*)alloc((size_t)CBC * DCH * 2);
    float* B2E          = (float*)alloc((size_t)CBC * 4);
    // per-layer stat buffers: [sums1|sqs1|sums2|sqs2] x NL x 512, zeroed once
    float* stats = (float*)alloc((size_t)4 * NL * 512 * 4);
    float* sums1 = stats + 0 * NL * 512;
    float* sqs1  = stats + 1 * NL * 512;
    float* sums2 = stats + 2 * NL * 512;
    float* sqs2  = stats + 3 * NL * 512;

    (void)hipMemsetAsync(stats, 0, (size_t)4 * NL * 512 * 4, stream);

    {
        const int NTOT = NL * DCH * CBC + NL * DCH * KW;
        prep_kernel<<<(NTOT + 255) / 256, 256, 0, stream>>>(w1, wd, W1S, WDS);
    }
    transpose_in<<<dim3(TT / 64, CBC / 64, BATCH), 256, 0, stream>>>(x, XA);

    const int NWG1 = (DCH / 128) * (TT / 128) * BATCH;   // 4*32*16 = 2048
    const int NWG2 = (CBC / 128) * (TT / 128) * BATCH;   // 2*32*16 = 1024

    for (int l = 0; l < NL; ++l) {
        // 1x1 conv CB->D + bias + PReLU, fused BN1 stats
        gemm_kernel<CBC, DCH / 128, true, false, true><<<NWG1, 256, 0, stream>>>(
            W1S + (size_t)l * DCH * CBC, XA, b1 + (size_t)l * DCH, a1 + l,
            Y, nullptr, nullptr, sums1 + l * 512, sqs1 + l * 512, DCH);
        // depthwise dilated conv (BN1 finalize fused) + bias + PReLU, fused BN2 stats
        dwconv_kernel<<<dim3(TT / 64, 2, BATCH), 256, 0, stream>>>(
            Y, sums1 + l * 512, sqs1 + l * 512, g1 + (size_t)l * DCH, be1 + (size_t)l * DCH,
            WDS + (size_t)l * DCH * KW, bd + (size_t)l * DCH, a2 + l, 1 << l,
            Z, sums2 + l * 512, sqs2 + l * 512);
        // fold BN2 (finalize fused) into GEMM2 weights
        fold_kernel<<<CBC, 256, 0, stream>>>(w2 + (size_t)l * CBC * DCH,
                                             sums2 + l * 512, sqs2 + l * 512,
                                             g2 + (size_t)l * DCH, be2 + (size_t)l * DCH,
                                             b2 + (size_t)l * CBC, W2E, B2E);
        // 1x1 conv D->CB (+ residual & fp32 [B][CB][T] on final layer)
        if (l < NL - 1) {
            gemm_kernel<DCH, CBC / 128, false, false, false><<<NWG2, 256, 0, stream>>>(
                W2E, Z, B2E, nullptr, XA, nullptr, nullptr, nullptr, nullptr, CBC);
        } else {
            gemm_kernel<DCH, CBC / 128, false, true, false><<<NWG2, 256, 0, stream>>>(
                W2E, Z, B2E, nullptr, nullptr, out, x, nullptr, nullptr, CBC);
        }
    }
}

// Round 7
// 578.626 us; speedup vs baseline: 1.6334x; 1.0045x over previous
//
#include <hip/hip_runtime.h>
#include <stdint.h>
#include <stddef.h>

#define NL   4
#define CBC  256
#define DCH  512
#define KW   3
#define BATCH 16
#define TT   4096
#define BT   (BATCH*TT)
#define EPSB 1e-5f

typedef __bf16 bf16_t;
typedef __attribute__((ext_vector_type(8))) __bf16 bf16x8;
typedef __attribute__((ext_vector_type(4))) float f32x4;
typedef __attribute__((ext_vector_type(8))) unsigned short us8;
typedef __attribute__((ext_vector_type(4))) unsigned short us4;

static __device__ __forceinline__ unsigned short f2bf(float f) {
    union { float f; uint32_t u; } v; v.f = f;
    uint32_t u = v.u;
    u += 0x7FFFu + ((u >> 16) & 1u);   // RNE
    return (unsigned short)(u >> 16);
}
static __device__ __forceinline__ float bf2f(unsigned short b) {
    union { uint32_t u; float f; } v; v.u = ((uint32_t)b) << 16;
    return v.f;
}
static __device__ __forceinline__ bf16x8 as_bf16x8(us8 u) {
    return __builtin_bit_cast(bf16x8, u);
}
static __device__ __forceinline__ float signf_(float w) {
    return (w > 0.f) ? 1.f : ((w < 0.f) ? -1.f : 0.f);
}

typedef __attribute__((address_space(1))) void as1_void;
typedef __attribute__((address_space(3))) void as3_void;
static __device__ __forceinline__ void gload_lds16(const unsigned short* g, unsigned short* l) {
    // 16B per lane, wave-uniform LDS base + lane*16 (guide §5: width=16 verified m97)
    __builtin_amdgcn_global_load_lds((as1_void*)g, (as3_void*)l, 16, 0, 0);
}

// ---------------------------------------------------------------------------
// Weight prep: sign(w1) -> bf16 [L][D][CB]; sign(wd) -> f32 [L][D][3]
// ---------------------------------------------------------------------------
__global__ void prep_kernel(const float* __restrict__ w1, const float* __restrict__ wd,
                            unsigned short* __restrict__ W1S, float* __restrict__ WDS) {
    const int NW1 = NL * DCH * CBC;
    const int NWD = NL * DCH * KW;
    int idx = blockIdx.x * 256 + threadIdx.x;
    if (idx < NW1) {
        W1S[idx] = f2bf(signf_(w1[idx]));
    } else if (idx < NW1 + NWD) {
        int j = idx - NW1;
        WDS[j] = signf_(wd[j]);
    }
}

// ---------------------------------------------------------------------------
// Input transpose: x [B][CB][T] f32  ->  XA [B*T][CB] bf16
// ---------------------------------------------------------------------------
__global__ void transpose_in(const float* __restrict__ x, unsigned short* __restrict__ XA) {
    __shared__ unsigned short tile[64][72];
    const int t0 = blockIdx.x * 64, c0 = blockIdx.y * 64, b = blockIdx.z;
    const int tid = threadIdx.x;
    {
        const int cl = tid >> 2;
        const int tl = (tid & 3) * 16;
        const float* src = x + ((size_t)(b * CBC + c0 + cl)) * TT + t0 + tl;
        #pragma unroll
        for (int u = 0; u < 16; u += 4) {
            float4 f = *(const float4*)(src + u);
            tile[cl][tl + u + 0] = f2bf(f.x);
            tile[cl][tl + u + 1] = f2bf(f.y);
            tile[cl][tl + u + 2] = f2bf(f.z);
            tile[cl][tl + u + 3] = f2bf(f.w);
        }
    }
    __syncthreads();
    {
        const int tr = tid >> 2;
        const int cc = (tid & 3) * 16;
        us8 o0, o1;
        #pragma unroll
        for (int e = 0; e < 8; ++e) { o0[e] = tile[cc + e][tr]; o1[e] = tile[cc + 8 + e][tr]; }
        unsigned short* dst = XA + ((size_t)(b * TT + t0 + tr)) * CBC + c0 + cc;
        *(us8*)dst = o0;
        *(us8*)(dst + 8) = o1;
    }
}

// ---------------------------------------------------------------------------
// GEMM: out[n][m] = sum_k A[m][k] * B[n][k] (+bias, optional PReLU)
// 128x128 tile, BK=32. T3+T4: 3-deep circular LDS staging with COUNTED
// vmcnt — the main loop never drains to 0, so each wave keeps the next
// stage's 4 loads in flight across the barrier (96KB/CU in flight >> the
// ~22KB Little's-law need for full HBM BW). Ledger (per wave, 4 loads per
// STAGE): entering iter k the outstanding ops are stage(k) [maybe landed]
// + stage(k+1); vmcnt(4) retires exactly stage(k). Barrier then publishes
// it block-wide. STAGE(k+2) after the barrier overwrites the buffer whose
// readers all crossed that barrier (in-order issue => their ds_reads
// retired before their MFMAs). Tail iter waits vmcnt(0). Post-loop barrier
// protects the sout union. sched_barrier(0) brackets every wait/barrier
// AND sits between STAGE and the ds_reads (rule #18: scheduler hoists ops
// past inline-asm waitcnts despite "memory" clobbers — round-2's failure,
// round-3-validated fix).
// LDS XOR swizzle both-sides (rule #21). Grid: 1D, bijective XCD-chunked
// swizzle, m-tiles innermost (L2 B-reuse).
// ---------------------------------------------------------------------------
template<int K, int NMT, bool PRELU, bool FINAL, bool STATS>
__global__ __launch_bounds__(256, 3)
void gemm_kernel(const unsigned short* __restrict__ A,
                 const unsigned short* __restrict__ Bact,
                 const float* __restrict__ bias,
                 const float* __restrict__ aptr,
                 unsigned short* __restrict__ Obf,
                 float* __restrict__ Ofin,
                 const float* __restrict__ resid,
                 float* __restrict__ sums, float* __restrict__ sqs,
                 int M) {
    __shared__ union {
        unsigned short stage[3][4][2048];    // [buf][A0,A1,B0,B1][64 rows x 32] = 48KB
        unsigned short sout[128 * 136];      // epilogue transpose (34KB)
    } sm;
    __shared__ float sstat[2][4][64];        // [sum/sq][wave][ch_local]

    const int tid = threadIdx.x;

    // bijective XCD-chunked swizzle (nwg % 8 == 0 always here, m204)
    const int nwg = NMT * (TT / 128) * BATCH;
    const int orig = blockIdx.x;
    const int logical = (orig & 7) * (nwg >> 3) + (orig >> 3);
    const int mt = logical % NMT;            // m-tile innermost -> same-XCD B reuse
    const int rest = logical / NMT;
    const int tt = rest & 31;                // TT/128 = 32 t-tiles
    const int bz = rest >> 5;
    const int t0 = tt * 128;
    const int m0 = mt * 128;
    const size_t n0 = (size_t)bz * TT + t0;

    const int lane = tid & 63;
    const int w    = tid >> 6;
    const int wm = w & 1, wn = w >> 1;
    const int l16 = lane & 15, q = lane >> 4;

    // staging: thread tid covers half-tile row tid>>2, swizzled 16B chunk
    const int rS = tid >> 2;
    const int cS = ((tid & 3) ^ ((tid >> 3) & 3)) * 8;   // chunk ^ ((row>>1)&3)
    const unsigned short* gA0 = A + (size_t)(m0 + rS) * K + cS;
    const unsigned short* gA1 = A + (size_t)(m0 + 64 + rS) * K + cS;
    const unsigned short* gB0 = Bact + (n0 + rS) * K + cS;
    const unsigned short* gB1 = Bact + (n0 + 64 + rS) * K + cS;
    const int wofs = w << 9;                  // per-wave 512-short (1KB) slice

    auto STAGE = [&](int step, int buf) {
        const int k0 = step * 32;
        unsigned short* sb = &sm.stage[buf][0][0];
        gload_lds16(gA0 + k0, sb + 0 * 2048 + wofs);
        gload_lds16(gA1 + k0, sb + 1 * 2048 + wofs);
        gload_lds16(gB0 + k0, sb + 2 * 2048 + wofs);
        gload_lds16(gB1 + k0, sb + 3 * 2048 + wofs);
    };

    f32x4 acc[4][4];
    #pragma unroll
    for (int i = 0; i < 4; ++i)
        #pragma unroll
        for (int j = 0; j < 4; ++j)
            acc[i][j] = (f32x4){0.f, 0.f, 0.f, 0.f};

    // read-side swizzle: same XOR as write side; ((i*16+l16)>>1)&3 == (l16>>1)&3
    const int csw = (q ^ ((l16 >> 1) & 3)) << 3;

    constexpr int NK = K / 32;
    static_assert(NK >= 2, "need 2-deep prologue");
    STAGE(0, 0);
    STAGE(1, 1);

    #pragma unroll
    for (int k = 0; k < NK; ++k) {
        // counted wait: retire exactly stage(k); keep stage(k+1) in flight
        if (k + 1 < NK) {
            asm volatile("s_waitcnt vmcnt(4)" ::: "memory");
        } else {
            asm volatile("s_waitcnt vmcnt(0)" ::: "memory");
        }
        __builtin_amdgcn_sched_barrier(0);
        __builtin_amdgcn_s_barrier();         // publish stage(k); prior readers done
        __builtin_amdgcn_sched_barrier(0);
        if (k + 2 < NK) STAGE(k + 2, (k + 2) % 3);
        __builtin_amdgcn_sched_barrier(0);    // reads below must not hoist above
        const unsigned short* sb = &sm.stage[k % 3][0][0];
        bf16x8 af[4], bfv[4];
        #pragma unroll
        for (int i = 0; i < 4; ++i)
            af[i] = as_bf16x8(*(const us8*)(sb + wm * 2048 + (i * 16 + l16) * 32 + csw));
        #pragma unroll
        for (int j = 0; j < 4; ++j)
            bfv[j] = as_bf16x8(*(const us8*)(sb + (2 + wn) * 2048 + (j * 16 + l16) * 32 + csw));
        #pragma unroll
        for (int i = 0; i < 4; ++i)
            #pragma unroll
            for (int j = 0; j < 4; ++j)
                acc[i][j] = __builtin_amdgcn_mfma_f32_16x16x32_bf16(af[i], bfv[j], acc[i][j], 0, 0, 0);
    }
    // post-loop barrier: every wave issued its final MFMAs (=> ds_reads
    // retired) before crossing; vmcnt drained at iter NK-1 => sout safe.
    __builtin_amdgcn_s_barrier();
    __builtin_amdgcn_sched_barrier(0);

    float alpha = 0.f;
    if constexpr (PRELU) alpha = aptr[0];

    if constexpr (FINAL) {
        #pragma unroll
        for (int i = 0; i < 4; ++i) {
            const int m_l = wm * 64 + i * 16 + q * 4;
            float bia[4];
            #pragma unroll
            for (int rg = 0; rg < 4; ++rg) bia[rg] = bias[m0 + m_l + rg];
            #pragma unroll
            for (int j = 0; j < 4; ++j) {
                const int n_l = wn * 64 + j * 16 + l16;
                const int t = t0 + n_l;
                #pragma unroll
                for (int rg = 0; rg < 4; ++rg) {
                    float v = acc[i][j][rg] + bia[rg];
                    size_t oidx = ((size_t)(bz * CBC + m0 + m_l + rg)) * TT + t;
                    Ofin[oidx] = v + resid[oidx];
                }
            }
        }
    } else {
        #pragma unroll
        for (int i = 0; i < 4; ++i) {
            const int m_l = wm * 64 + i * 16 + q * 4;
            float bia[4];
            #pragma unroll
            for (int rg = 0; rg < 4; ++rg) bia[rg] = bias[m0 + m_l + rg];
            #pragma unroll
            for (int j = 0; j < 4; ++j) {
                const int n_l = wn * 64 + j * 16 + l16;
                us4 pkv;
                #pragma unroll
                for (int rg = 0; rg < 4; ++rg) {
                    float v = acc[i][j][rg] + bia[rg];
                    if (PRELU) v = (v >= 0.f) ? v : alpha * v;
                    pkv[rg] = f2bf(v);
                }
                *(us4*)&sm.sout[n_l * 136 + m_l] = pkv;
            }
            if constexpr (STATS) {
                #pragma unroll
                for (int rg = 0; rg < 4; ++rg) {
                    float sv = 0.f, sq2 = 0.f;
                    #pragma unroll
                    for (int j = 0; j < 4; ++j) {
                        float v = acc[i][j][rg] + bia[rg];
                        if (PRELU) v = (v >= 0.f) ? v : alpha * v;
                        sv += v; sq2 += v * v;
                    }
                    #pragma unroll
                    for (int msk = 1; msk < 16; msk <<= 1) {
                        sv  += __shfl_xor(sv,  msk, 64);
                        sq2 += __shfl_xor(sq2, msk, 64);
                    }
                    if (l16 == 0) {
                        const int cl = i * 16 + q * 4 + rg;   // channel local to wm
                        sstat[0][w][cl] = sv;
                        sstat[1][w][cl] = sq2;
                    }
                }
            }
        }
        __syncthreads();
        const int rr = tid >> 4;
        const int c8 = (tid & 15) * 8;
        #pragma unroll
        for (int p = 0; p < 8; ++p) {
            const int n_l = p * 16 + rr;
            us8 v = *(const us8*)&sm.sout[n_l * 136 + c8];
            *(us8*)(Obf + (n0 + n_l) * M + m0 + c8) = v;
        }
        if constexpr (STATS) {
            if (tid < 128) {
                const int wmc = tid >> 6, cl = tid & 63;
                float S = sstat[0][wmc][cl] + sstat[0][wmc + 2][cl];
                float Q = sstat[1][wmc][cl] + sstat[1][wmc + 2][cl];
                atomicAdd(&sums[m0 + tid], S);
                atomicAdd(&sqs[m0 + tid], Q);
            }
        }
    }
}

// ---------------------------------------------------------------------------
// Depthwise dilated causal conv + bias + PReLU, fused Z-stats.
// UNCHANGED from round 6 (channel-split grid + 16B/lane us8 layout,
// verified). Steady blocks use the exact BN1 fold (wk in {+-1,0}).
// grid = (TT/64, 2, BATCH), block 256.
// ---------------------------------------------------------------------------
__global__ __launch_bounds__(256)
void dwconv_kernel(const unsigned short* __restrict__ Y,
                   const float* __restrict__ sums1, const float* __restrict__ sqs1,
                   const float* __restrict__ g1, const float* __restrict__ be1,
                   const float* __restrict__ wds, const float* __restrict__ bd,
                   const float* __restrict__ a2p, int dil,
                   unsigned short* __restrict__ Z,
                   float* __restrict__ sums2, float* __restrict__ sqs2) {
    __shared__ float ssum[4][256];
    __shared__ float ssq[4][256];
    const int b = blockIdx.z;
    const int half = blockIdx.y;
    const int t0 = blockIdx.x * 64;
    const int tid = threadIdx.x;
    const int w = tid >> 6;
    const int lane = tid & 63;
    const int r = lane >> 5;              // row sub-index within wave (0/1)
    const int cl = (lane & 31) * 8;       // channel local to this half
    const int c0 = half * 256 + cl;       // global channel base (8 channels)
    const float alpha = a2p[0];

    // fused BN1 finalize (per-lane, 8 channels) + raw weights
    float s8[8], sh8[8], wv0[8], wv1[8], wv2[8], bb8[8];
    const float inv = 1.f / (float)BT;
    #pragma unroll
    for (int e = 0; e < 8; ++e) {
        const int d = c0 + e;
        float mean = sums1[d] * inv;
        float var = sqs1[d] * inv - mean * mean;
        float sc = g1[d] * rsqrtf(var + EPSB);
        s8[e] = sc;
        sh8[e] = be1[d] - mean * sc;
        wv0[e] = wds[d * 3 + 0]; wv1[e] = wds[d * 3 + 1]; wv2[e] = wds[d * 3 + 2];
        bb8[e] = bd[d];
    }

    float asum[8], asq[8];
    #pragma unroll
    for (int e = 0; e < 8; ++e) { asum[e] = 0.f; asq[e] = 0.f; }

    if (blockIdx.x == 0) {
        // boundary block: conditional taps (t < 2*dil possible), unfolded BN
        for (int it = 0; it < 8; ++it) {
            const int t = it * 8 + 2 * w + r;
            const size_t base = ((size_t)b * TT + t) * DCH + c0;
            float acc[8];
            {
                us8 y0 = *(const us8*)&Y[base];
                #pragma unroll
                for (int e = 0; e < 8; ++e)
                    acc[e] = wv2[e] * (s8[e] * bf2f(y0[e]) + sh8[e]) + bb8[e];
            }
            if (t >= dil) {
                us8 y1 = *(const us8*)&Y[base - (size_t)dil * DCH];
                #pragma unroll
                for (int e = 0; e < 8; ++e)
                    acc[e] += wv1[e] * (s8[e] * bf2f(y1[e]) + sh8[e]);
            }
            if (t >= 2 * dil) {
                us8 y2 = *(const us8*)&Y[base - (size_t)(2 * dil) * DCH];
                #pragma unroll
                for (int e = 0; e < 8; ++e)
                    acc[e] += wv0[e] * (s8[e] * bf2f(y2[e]) + sh8[e]);
            }
            us8 o;
            #pragma unroll
            for (int e = 0; e < 8; ++e) {
                float v = acc[e];
                v = (v >= 0.f) ? v : alpha * v;
                asum[e] += v; asq[e] += v * v;
                o[e] = f2bf(v);
            }
            *(us8*)&Z[base] = o;
        }
    } else {
        // steady blocks: exact BN fold (w = +-1/0), unconditional taps
        float W0s[8], W1s[8], W2s[8], shall[8];
        #pragma unroll
        for (int e = 0; e < 8; ++e) {
            W0s[e] = wv0[e] * s8[e];
            W1s[e] = wv1[e] * s8[e];
            W2s[e] = wv2[e] * s8[e];
            shall[e] = (wv0[e] + wv1[e] + wv2[e]) * sh8[e] + bb8[e];
        }
        const size_t d1 = (size_t)dil * DCH, d2 = 2 * d1;
        for (int it = 0; it < 8; ++it) {
            const int t = t0 + it * 8 + 2 * w + r;
            const size_t base = ((size_t)b * TT + t) * DCH + c0;
            us8 y0 = *(const us8*)&Y[base];
            us8 y1 = *(const us8*)&Y[base - d1];
            us8 y2 = *(const us8*)&Y[base - d2];
            us8 o;
            #pragma unroll
            for (int e = 0; e < 8; ++e) {
                float v = W2s[e] * bf2f(y0[e]) + W1s[e] * bf2f(y1[e])
                        + W0s[e] * bf2f(y2[e]) + shall[e];
                v = (v >= 0.f) ? v : alpha * v;
                asum[e] += v; asq[e] += v * v;
                o[e] = f2bf(v);
            }
            *(us8*)&Z[base] = o;
        }
    }

    // combine the two row-groups (lane l and l+32 hold the same channels)
    #pragma unroll
    for (int e = 0; e < 8; ++e) {
        asum[e] += __shfl_xor(asum[e], 32, 64);
        asq[e]  += __shfl_xor(asq[e], 32, 64);
    }
    if (lane < 32) {
        #pragma unroll
        for (int e = 0; e < 8; ++e) { ssum[w][cl + e] = asum[e]; ssq[w][cl + e] = asq[e]; }
    }
    __syncthreads();
    {
        const int ch = tid;   // 0..255 (one channel per thread, local to half)
        float S = ssum[0][ch] + ssum[1][ch] + ssum[2][ch] + ssum[3][ch];
        float Q = ssq[0][ch] + ssq[1][ch] + ssq[2][ch] + ssq[3][ch];
        atomicAdd(&sums2[half * 256 + ch], S);
        atomicAdd(&sqs2[half * 256 + ch], Q);
    }
}

// ---------------------------------------------------------------------------
// Fold BN2 into GEMM2 weights (BN2 finalize fused in):
// sc2/shf2 computed per-thread from raw sums2/sqs2.
// W2eff[c][d] = sign(w2[c][d]) * sc2[d] (bf16)
// b2eff[c] = b2[c] + sum_d sign(w2[c][d]) * shf2[d]
// ---------------------------------------------------------------------------
__global__ void fold_kernel(const float* __restrict__ w2,
                            const float* __restrict__ sums2, const float* __restrict__ sqs2,
                            const float* __restrict__ g2, const float* __restrict__ be2,
                            const float* __restrict__ b2,
                            unsigned short* __restrict__ W2E, float* __restrict__ B2E) {
    __shared__ float red[256];
    const int c = blockIdx.x, tid = threadIdx.x;
    const float inv = 1.f / (float)BT;
    float part = 0.f;
    for (int d = tid; d < DCH; d += 256) {
        float mean = sums2[d] * inv;
        float var = sqs2[d] * inv - mean * mean;
        float sc = g2[d] * rsqrtf(var + EPSB);
        float shf = be2[d] - mean * sc;
        float w = w2[(size_t)c * DCH + d];
        float sgn = signf_(w);
        W2E[(size_t)c * DCH + d] = f2bf(sgn * sc);
        part += sgn * shf;
    }
    red[tid] = part;
    __syncthreads();
    for (int off = 128; off > 0; off >>= 1) {
        if (tid < off) red[tid] += red[tid + off];
        __syncthreads();
    }
    if (tid == 0) B2E[c] = b2[c] + red[0];
}

// ---------------------------------------------------------------------------
extern "C" void kernel_launch(void* const* d_in, const int* in_sizes, int n_in,
                              void* d_out, int out_size, void* d_ws, size_t ws_size,
                              hipStream_t stream) {
    const float* x   = (const float*)d_in[0];
    const float* w1  = (const float*)d_in[1];
    const float* b1  = (const float*)d_in[2];
    const float* a1  = (const float*)d_in[3];
    const float* g1  = (const float*)d_in[4];
    const float* be1 = (const float*)d_in[5];
    const float* wd  = (const float*)d_in[6];
    const float* bd  = (const float*)d_in[7];
    const float* a2  = (const float*)d_in[8];
    const float* g2  = (const float*)d_in[9];
    const float* be2 = (const float*)d_in[10];
    const float* w2  = (const float*)d_in[11];
    const float* b2  = (const float*)d_in[12];
    float* out = (float*)d_out;

    char* ws = (char*)d_ws;
    size_t off = 0;
    auto alloc = [&](size_t bytes) -> void* {
        void* p = ws + off;
        off += (bytes + 255) & ~(size_t)255;
        return p;
    };
    unsigned short* XA  = (unsigned short*)alloc((size_t)BT * CBC * 2);
    unsigned short* Y   = (unsigned short*)alloc((size_t)BT * DCH * 2);
    unsigned short* Z   = (unsigned short*)alloc((size_t)BT * DCH * 2);
    unsigned short* W1S = (unsigned short*)alloc((size_t)NL * DCH * CBC * 2);
    float* WDS          = (float*)alloc((size_t)NL * DCH * KW * 4);
    unsigned short* W2E = (unsigned short*)alloc((size_t)CBC * DCH * 2);
    float* B2E          = (float*)alloc((size_t)CBC * 4);
    // per-layer stat buffers: [sums1|sqs1|sums2|sqs2] x NL x 512, zeroed once
    float* stats = (float*)alloc((size_t)4 * NL * 512 * 4);
    float* sums1 = stats + 0 * NL * 512;
    float* sqs1  = stats + 1 * NL * 512;
    float* sums2 = stats + 2 * NL * 512;
    float* sqs2  = stats + 3 * NL * 512;

    (void)hipMemsetAsync(stats, 0, (size_t)4 * NL * 512 * 4, stream);

    {
        const int NTOT = NL * DCH * CBC + NL * DCH * KW;
        prep_kernel<<<(NTOT + 255) / 256, 256, 0, stream>>>(w1, wd, W1S, WDS);
    }
    transpose_in<<<dim3(TT / 64, CBC / 64, BATCH), 256, 0, stream>>>(x, XA);

    const int NWG1 = (DCH / 128) * (TT / 128) * BATCH;   // 4*32*16 = 2048
    const int NWG2 = (CBC / 128) * (TT / 128) * BATCH;   // 2*32*16 = 1024

    for (int l = 0; l < NL; ++l) {
        // 1x1 conv CB->D + bias + PReLU, fused BN1 stats
        gemm_kernel<CBC, DCH / 128, true, false, true><<<NWG1, 256, 0, stream>>>(
            W1S + (size_t)l * DCH * CBC, XA, b1 + (size_t)l * DCH, a1 + l,
            Y, nullptr, nullptr, sums1 + l * 512, sqs1 + l * 512, DCH);
        // depthwise dilated conv (BN1 finalize fused) + bias + PReLU, fused BN2 stats
        dwconv_kernel<<<dim3(TT / 64, 2, BATCH), 256, 0, stream>>>(
            Y, sums1 + l * 512, sqs1 + l * 512, g1 + (size_t)l * DCH, be1 + (size_t)l * DCH,
            WDS + (size_t)l * DCH * KW, bd + (size_t)l * DCH, a2 + l, 1 << l,
            Z, sums2 + l * 512, sqs2 + l * 512);
        // fold BN2 (finalize fused) into GEMM2 weights
        fold_kernel<<<CBC, 256, 0, stream>>>(w2 + (size_t)l * CBC * DCH,
                                             sums2 + l * 512, sqs2 + l * 512,
                                             g2 + (size_t)l * DCH, be2 + (size_t)l * DCH,
                                             b2 + (size_t)l * CBC, W2E, B2E);
        // 1x1 conv D->CB (+ residual & fp32 [B][CB][T] on final layer)
        if (l < NL - 1) {
            gemm_kernel<DCH, CBC / 128, false, false, false><<<NWG2, 256, 0, stream>>>(
                W2E, Z, B2E, nullptr, XA, nullptr, nullptr, nullptr, nullptr, CBC);
        } else {
            gemm_kernel<DCH, CBC / 128, false, true, false><<<NWG2, 256, 0, stream>>>(
                W2E, Z, B2E, nullptr, nullptr, out, x, nullptr, nullptr, CBC);
        }
    }
}